// Round 1
// baseline (68.508 us; speedup 1.0000x reference)
//
#include <hip/hip_runtime.h>
#include <math.h>

// Problem constants
#define NBINS 2049       // F
#define NFAST 4096
#define NHALF 2048       // complex FFT size
#define NXC   599        // 2*NLAG-1
#define LST   640        // ws row stride (floats), 2560B = cacheline aligned
#define TWO_PI 6.283185307179586f

// LDS padding: +1 float per 32 → breaks power-of-2 stride bank conflicts
#define PADIDX(i) ((i) + ((i) >> 5))

__device__ inline void dft4i(float& r0, float& i0, float& r1, float& i1,
                             float& r2, float& i2, float& r3, float& i3) {
    // inverse (e^{+i}) 4-point DFT in place
    float t0r = r0 + r2, t0i = i0 + i2;
    float t1r = r0 - r2, t1i = i0 - i2;
    float t2r = r1 + r3, t2i = i1 + i3;
    float t3r = r1 - r3, t3i = i1 - i3;
    r0 = t0r + t2r; i0 = t0i + t2i;
    r2 = t0r - t2r; i2 = t0i - t2i;
    r1 = t1r - t3i; i1 = t1i + t3r;   // t1 + i*t3
    r3 = t1r + t3i; i3 = t1i - t3r;   // t1 - i*t3
}

__device__ inline void radix8_bfly(float r[8], float im[8]) {
    // inverse 8-point DFT: split even/odd, two DFT4, combine with w = e^{i*pi/4}
    float er0 = r[0], ei0 = im[0], er1 = r[2], ei1 = im[2];
    float er2 = r[4], ei2 = im[4], er3 = r[6], ei3 = im[6];
    float or0 = r[1], oi0 = im[1], or1 = r[3], oi1 = im[3];
    float or2 = r[5], oi2 = im[5], or3 = r[7], oi3 = im[7];
    dft4i(er0, ei0, er1, ei1, er2, ei2, er3, ei3);
    dft4i(or0, oi0, or1, oi1, or2, oi2, or3, oi3);
    const float C = 0.70710678118654752f;
    float w1r = C * (or1 - oi1), w1i = C * (or1 + oi1);   // e^{i pi/4} * o1
    float w2r = -oi2,            w2i = or2;               // i * o2
    float w3r = -C * (or3 + oi3), w3i = C * (or3 - oi3);  // e^{3i pi/4} * o3
    r[0] = er0 + or0; im[0] = ei0 + oi0;
    r[4] = er0 - or0; im[4] = ei0 - oi0;
    r[1] = er1 + w1r; im[1] = ei1 + w1i;
    r[5] = er1 - w1r; im[5] = ei1 - w1i;
    r[2] = er2 + w2r; im[2] = ei2 + w2i;
    r[6] = er2 - w2r; im[6] = ei2 - w2i;
    r[3] = er3 + w3r; im[3] = ei3 + w3i;
    r[7] = er3 - w3r; im[7] = ei3 - w3i;
}

// Stockham DIF radix-8 stage (inverse sign). Invariant: n*s = 2048, s*m = 256.
// Reads x[tid + 256*j]; writes y[q + s*(8p+k)] with twiddle w^(k*p), w = e^{+2pi i/n}.
template <int LOG2S>
__device__ inline void radix8_stage(const float* __restrict__ xr, const float* __restrict__ xi,
                                    float* __restrict__ yr, float* __restrict__ yi,
                                    int tid, float angStep) {
    const int s = 1 << LOG2S;
    const int q = tid & (s - 1);
    const int p = tid >> LOG2S;
    float r[8], im[8];
#pragma unroll
    for (int j = 0; j < 8; ++j) {
        int idx = PADIDX(tid + 256 * j);
        r[j] = xr[idx]; im[j] = xi[idx];
    }
    radix8_bfly(r, im);
    float sn, cs;
    __sincosf(angStep * (float)p, &sn, &cs);
    const float wr = cs, wi = sn;
    const int wb = q + (p << (LOG2S + 3));
    int idx0 = PADIDX(wb);
    yr[idx0] = r[0]; yi[idx0] = im[0];
    float cwr = wr, cwi = wi;
#pragma unroll
    for (int k = 1; k < 8; ++k) {
        float zr = r[k] * cwr - im[k] * cwi;
        float zi = r[k] * cwi + im[k] * cwr;
        int idx = PADIDX(wb + (k << LOG2S));
        yr[idx] = zr; yi[idx] = zi;
        float nwr = cwr * wr - cwi * wi;   // next power of w
        float nwi = cwr * wi + cwi * wr;
        cwr = nwr; cwi = nwi;
    }
}

__device__ inline void radix4_final(const float* __restrict__ xr, const float* __restrict__ xi,
                                    float* __restrict__ yr, float* __restrict__ yi, int tid) {
    // n=4, s=512, m=1: twiddles are 1. Each thread does 2 butterflies.
#pragma unroll
    for (int h = 0; h < 2; ++h) {
        int q = tid + 256 * h;
        float r0 = xr[PADIDX(q)],          i0 = xi[PADIDX(q)];
        float r1 = xr[PADIDX(q + 512)],    i1 = xi[PADIDX(q + 512)];
        float r2 = xr[PADIDX(q + 1024)],   i2 = xi[PADIDX(q + 1024)];
        float r3 = xr[PADIDX(q + 1536)],   i3 = xi[PADIDX(q + 1536)];
        dft4i(r0, i0, r1, i1, r2, i2, r3, i3);
        int a0 = PADIDX(q);        yr[a0] = r0; yi[a0] = i0;
        int a1 = PADIDX(q + 512);  yr[a1] = r1; yi[a1] = i1;
        int a2 = PADIDX(q + 1024); yr[a2] = r2; yi[a2] = i2;
        int a3 = PADIDX(q + 1536); yr[a3] = r3; yi[a3] = i3;
    }
}

// Kernel 1: per (b,c) row — cross-spectrum, hermitian pack, 2048-pt inverse FFT, lag extract.
__global__ __launch_bounds__(256) void k1_fft(const float2* __restrict__ d1,
                                              const float2* __restrict__ d2,
                                              float* __restrict__ ws) {
    __shared__ float Ar[2112], Ai[2112], Br[2112], Bi[2112];
    const int row = blockIdx.x;                 // b*128 + c
    const float2* p1 = d1 + (long)row * NBINS;
    const float2* p2 = d2 + (long)row * NBINS;
    const int t = threadIdx.x;

    // Pack: Z[k] = E[k] + i*e^{+2pi i k/4096}*D[k], E=(X[k]+conj(X[2048-k]))/2, D=(X[k]-conj(X[2048-k]))/2
    // X[k] = conj(c1[k])*c2[k]. Imag of bins 0 and 2048 zeroed (pocketfft c2r semantics).
#pragma unroll
    for (int j = 0; j < 4; ++j) {
        int k = t + 256 * j;       // 0..1023
        int m = 2048 - k;          // 2048..1025
        float2 a = p1[k],  bb = p2[k];
        float2 am = p1[m], bm = p2[m];
        float xr = a.x * bb.x + a.y * bb.y;
        float xi = a.x * bb.y - a.y * bb.x;
        float yr2 = am.x * bm.x + am.y * bm.y;
        float yi2 = am.x * bm.y - am.y * bm.x;
        if (k == 0) { xi = 0.0f; yi2 = 0.0f; }
        float er = 0.5f * (xr + yr2), ei = 0.5f * (xi - yi2);
        float dr = 0.5f * (xr - yr2), di = 0.5f * (xi + yi2);
        float sn, cs;
        __sincosf((float)k * (TWO_PI / 4096.0f), &sn, &cs);
        // Z[k] = E + i*t_k*D,  i*t_k = (-sn, cs)
        Ar[PADIDX(k)] = er - sn * dr - cs * di;
        Ai[PADIDX(k)] = ei + cs * dr - sn * di;
        if (k != 0) {
            // Z[m] = E' + i*t_m*D' with E'=(er,-ei), D'=(-dr,di), i*t_m = (-sn,-cs)
            Ar[PADIDX(m)] = er + sn * dr + cs * di;
            Ai[PADIDX(m)] = -ei + cs * dr - sn * di;
        }
    }
    if (t == 0) {   // Z[1024] = conj(X[1024])
        float2 a = p1[1024], bb = p2[1024];
        Ar[PADIDX(1024)] = a.x * bb.x + a.y * bb.y;
        Ai[PADIDX(1024)] = -(a.x * bb.y - a.y * bb.x);
    }
    __syncthreads();
    radix8_stage<0>(Ar, Ai, Br, Bi, t, TWO_PI / 2048.0f);
    __syncthreads();
    radix8_stage<3>(Br, Bi, Ar, Ai, t, TWO_PI / 256.0f);
    __syncthreads();
    radix8_stage<6>(Ar, Ai, Br, Bi, t, TWO_PI / 32.0f);
    __syncthreads();
    radix4_final(Br, Bi, Ar, Ai, t);
    __syncthreads();

    // z[m] (unscaled) now in A, natural order. x[2m]=Re z[m]/2048, x[2m+1]=Im z[m]/2048.
    // xcor[l] = x[(3797 + l) & 4095], l = 0..598
    const float scale = 1.0f / 2048.0f;
    float* wrow = ws + (long)row * LST;
    for (int l = t; l < NXC; l += 256) {
        int n = (3797 + l) & 4095;
        int mm = n >> 1;
        float v = (n & 1) ? Ai[PADIDX(mm)] : Ar[PADIDX(mm)];
        wrow[l] = v * scale;
    }
}

// Kernel 2: channel moving-average (window 20, zero-padded edges, /20), then max/|min| pick.
__global__ __launch_bounds__(256) void k2_win(const float* __restrict__ ws,
                                              const int* __restrict__ e1,
                                              const int* __restrict__ e2,
                                              float* __restrict__ out) {
    const int bc = blockIdx.x;
    const int b = bc >> 7, c = bc & 127;
    const int t = threadIdx.x;
    const float* base = ws + (long)(b * 128) * LST;

    float vmax = -3.0e38f; int imax = 0;
    float vmin = 3.0e38f;  int imin = 0;
    for (int l = t; l < NXC; l += 256) {
        float s = 0.0f;
#pragma unroll
        for (int w = 0; w < 20; ++w) {
            int cc2 = c - 10 + w;               // window [c-10, c+9]
            if (cc2 >= 0 && cc2 < 128)          // uniform per block
                s += base[cc2 * LST + l];
        }
        s *= (1.0f / 20.0f);
        if (s > vmax) { vmax = s; imax = l; }
        if (s < vmin) { vmin = s; imin = l; }
    }

    __shared__ float smax[256], smin[256];
    __shared__ int   sxi[256], sni[256];
    smax[t] = vmax; sxi[t] = imax; smin[t] = vmin; sni[t] = imin;
    __syncthreads();
    for (int off = 128; off > 0; off >>= 1) {
        if (t < off) {
            float v2 = smax[t + off]; int i2 = sxi[t + off];
            if (v2 > smax[t] || (v2 == smax[t] && i2 < sxi[t])) { smax[t] = v2; sxi[t] = i2; }
            float u2 = smin[t + off]; int j2 = sni[t + off];
            if (u2 < smin[t] || (u2 == smin[t] && j2 < sni[t])) { smin[t] = u2; sni[t] = j2; }
        }
        __syncthreads();
    }
    if (t == 0) {
        float vx = smax[0], vn = smin[0];
        int ix = sxi[0], in_ = sni[0];
        bool ineg = fabsf(vn) > vx;
        float ccv = ineg ? vn : vx;
        int idx = ineg ? in_ : ix;
        out[bc] = ccv;
        out[4096 + bc] = (float)(idx - 299) * 0.01f;   // (idx - NLAG + 1) * DT
    }
    if (bc == 0 && t < 32) out[8192 + t] = (float)e1[t];
    if (bc == 1 && t < 32) out[8224 + t] = (float)e2[t];
}

extern "C" void kernel_launch(void* const* d_in, const int* in_sizes, int n_in,
                              void* d_out, int out_size, void* d_ws, size_t ws_size,
                              hipStream_t stream) {
    const float2* d1 = (const float2*)d_in[0];
    const float2* d2 = (const float2*)d_in[1];
    const int* e1 = (const int*)d_in[2];
    const int* e2 = (const int*)d_in[3];
    float* out = (float*)d_out;
    float* ws = (float*)d_ws;

    k1_fft<<<dim3(4096), dim3(256), 0, stream>>>(d1, d2, ws);
    k2_win<<<dim3(4096), dim3(256), 0, stream>>>(ws, e1, e2, out);
}

// Round 2
// 49.111 us; speedup vs baseline: 1.3950x; 1.3950x over previous
//
#include <hip/hip_runtime.h>
#include <math.h>

// Problem constants
#define NBINS 2049       // F
#define NXC   599        // 2*NLAG-1
#define LST   640        // ws row stride (floats)
#define TWO_PI 6.283185307179586f

// LDS padding: +1 float per 32 → breaks power-of-2 stride bank conflicts
#define PADIDX(i) ((i) + ((i) >> 5))

__device__ inline void dft4i(float& r0, float& i0, float& r1, float& i1,
                             float& r2, float& i2, float& r3, float& i3) {
    // inverse (e^{+i}) 4-point DFT in place
    float t0r = r0 + r2, t0i = i0 + i2;
    float t1r = r0 - r2, t1i = i0 - i2;
    float t2r = r1 + r3, t2i = i1 + i3;
    float t3r = r1 - r3, t3i = i1 - i3;
    r0 = t0r + t2r; i0 = t0i + t2i;
    r2 = t0r - t2r; i2 = t0i - t2i;
    r1 = t1r - t3i; i1 = t1i + t3r;   // t1 + i*t3
    r3 = t1r + t3i; i3 = t1i - t3r;   // t1 - i*t3
}

__device__ inline void radix8_bfly(float r[8], float im[8]) {
    // inverse 8-point DFT: split even/odd, two DFT4, combine with w = e^{i*pi/4}
    float er0 = r[0], ei0 = im[0], er1 = r[2], ei1 = im[2];
    float er2 = r[4], ei2 = im[4], er3 = r[6], ei3 = im[6];
    float or0 = r[1], oi0 = im[1], or1 = r[3], oi1 = im[3];
    float or2 = r[5], oi2 = im[5], or3 = r[7], oi3 = im[7];
    dft4i(er0, ei0, er1, ei1, er2, ei2, er3, ei3);
    dft4i(or0, oi0, or1, oi1, or2, oi2, or3, oi3);
    const float C = 0.70710678118654752f;
    float w1r = C * (or1 - oi1), w1i = C * (or1 + oi1);   // e^{i pi/4} * o1
    float w2r = -oi2,            w2i = or2;               // i * o2
    float w3r = -C * (or3 + oi3), w3i = C * (or3 - oi3);  // e^{3i pi/4} * o3
    r[0] = er0 + or0; im[0] = ei0 + oi0;
    r[4] = er0 - or0; im[4] = ei0 - oi0;
    r[1] = er1 + w1r; im[1] = ei1 + w1i;
    r[5] = er1 - w1r; im[5] = ei1 - w1i;
    r[2] = er2 + w2r; im[2] = ei2 + w2i;
    r[6] = er2 - w2r; im[6] = ei2 - w2i;
    r[3] = er3 + w3r; im[3] = ei3 + w3i;
    r[7] = er3 - w3r; im[7] = ei3 - w3i;
}

// In-place DIF radix-8 stage (inverse sign), sub-FFT length L = 8*span, span = 1<<SL.
// Thread t: sub-block = t>>SL, i = t&(span-1). Reads/writes positions base + j*span.
// After butterfly, multiply u_k by e^{+2pi i * i * k / L}. Output ends digit-reversed.
template <int SL>
__device__ inline void dif8_stage(float* __restrict__ ar, float* __restrict__ ai, int t) {
    const int span = 1 << SL;
    const int i = t & (span - 1);
    const int base = ((t >> SL) << (SL + 3)) + i;
    float r[8], im[8];
    int idx[8];
#pragma unroll
    for (int j = 0; j < 8; ++j) {
        idx[j] = PADIDX(base + (j << SL));
        r[j] = ar[idx[j]]; im[j] = ai[idx[j]];
    }
    radix8_bfly(r, im);
    float sn, cs;
    __sincosf((TWO_PI / (float)(span * 8)) * (float)i, &sn, &cs);
    ar[idx[0]] = r[0]; ai[idx[0]] = im[0];
    float cwr = cs, cwi = sn;
#pragma unroll
    for (int k = 1; k < 8; ++k) {
        float zr = r[k] * cwr - im[k] * cwi;
        float zi = r[k] * cwi + im[k] * cwr;
        ar[idx[k]] = zr; ai[idx[k]] = zi;
        float nwr = cwr * cs - cwi * sn;   // next power of w
        float nwi = cwr * sn + cwi * cs;
        cwr = nwr; cwi = nwi;
    }
}

// Final in-place radix-4 stage (L=4, span=1): no twiddles, 2 butterflies per thread.
__device__ inline void dif4_final(float* __restrict__ ar, float* __restrict__ ai, int t) {
#pragma unroll
    for (int h = 0; h < 2; ++h) {
        int base = (t + 256 * h) << 2;
        int i0 = PADIDX(base), i1 = PADIDX(base + 1), i2 = PADIDX(base + 2), i3 = PADIDX(base + 3);
        float r0 = ar[i0], m0 = ai[i0], r1 = ar[i1], m1 = ai[i1];
        float r2 = ar[i2], m2 = ai[i2], r3 = ar[i3], m3 = ai[i3];
        dft4i(r0, m0, r1, m1, r2, m2, r3, m3);
        ar[i0] = r0; ai[i0] = m0; ar[i1] = r1; ai[i1] = m1;
        ar[i2] = r2; ai[i2] = m2; ar[i3] = r3; ai[i3] = m3;
    }
}

// Kernel 1: per (b,c) row — cross-spectrum, hermitian pack, in-place 2048-pt inverse
// DIF FFT (digit-reversed output), lag extract with digit-reversal folded into index.
__global__ __launch_bounds__(256) void k1_fft(const float2* __restrict__ d1,
                                              const float2* __restrict__ d2,
                                              float* __restrict__ ws) {
    __shared__ float Ar[2112], Ai[2112];   // 16.9 KB total → 8 blocks/CU
    const int row = blockIdx.x;            // b*128 + c
    const float2* p1 = d1 + (long)row * NBINS;
    const float2* p2 = d2 + (long)row * NBINS;
    const int t = threadIdx.x;

    // Pack: Z[k] = E[k] + i*e^{+2pi i k/4096}*D[k], E=(X[k]+conj(X[2048-k]))/2, D=(X[k]-conj(X[2048-k]))/2
    // X[k] = conj(c1[k])*c2[k]. Imag of bins 0 and 2048 zeroed (pocketfft c2r semantics).
#pragma unroll
    for (int j = 0; j < 4; ++j) {
        int k = t + 256 * j;       // 0..1023
        int m = 2048 - k;          // 2048..1025
        float2 a = p1[k],  bb = p2[k];
        float2 am = p1[m], bm = p2[m];
        float xr = a.x * bb.x + a.y * bb.y;
        float xi = a.x * bb.y - a.y * bb.x;
        float yr2 = am.x * bm.x + am.y * bm.y;
        float yi2 = am.x * bm.y - am.y * bm.x;
        if (k == 0) { xi = 0.0f; yi2 = 0.0f; }
        float er = 0.5f * (xr + yr2), ei = 0.5f * (xi - yi2);
        float dr = 0.5f * (xr - yr2), di = 0.5f * (xi + yi2);
        float sn, cs;
        __sincosf((float)k * (TWO_PI / 4096.0f), &sn, &cs);
        // Z[k] = E + i*t_k*D,  i*t_k = (-sn, cs)
        Ar[PADIDX(k)] = er - sn * dr - cs * di;
        Ai[PADIDX(k)] = ei + cs * dr - sn * di;
        if (k != 0) {
            // Z[m] = E' + i*t_m*D' with E'=(er,-ei), D'=(-dr,di), i*t_m = (-sn,-cs)
            Ar[PADIDX(m)] = er + sn * dr + cs * di;
            Ai[PADIDX(m)] = -ei + cs * dr - sn * di;
        }
    }
    if (t == 0) {   // Z[1024] = conj(X[1024])
        float2 a = p1[1024], bb = p2[1024];
        Ar[PADIDX(1024)] = a.x * bb.x + a.y * bb.y;
        Ai[PADIDX(1024)] = -(a.x * bb.y - a.y * bb.x);
    }
    __syncthreads();
    dif8_stage<8>(Ar, Ai, t);    // L=2048
    __syncthreads();
    dif8_stage<5>(Ar, Ai, t);    // L=256
    __syncthreads();
    dif8_stage<2>(Ar, Ai, t);    // L=32
    __syncthreads();
    dif4_final(Ar, Ai, t);       // L=4
    __syncthreads();

    // z[m] (unscaled, digit-reversed) in A. x[2m]=Re z[m]/2048, x[2m+1]=Im z[m]/2048.
    // xcor[l] = x[(3797 + l) & 4095]; storage pos(m) = 256*(m&7)+32*((m>>3)&7)+4*((m>>6)&7)+(m>>9)
    const float scale = 1.0f / 2048.0f;
    float* wrow = ws + (long)row * LST;
    for (int l = t; l < NXC; l += 256) {
        int n = (3797 + l) & 4095;
        int mm = n >> 1;
        int pos = ((mm & 7) << 8) | (((mm >> 3) & 7) << 5) | (((mm >> 6) & 7) << 2) | (mm >> 9);
        float v = (n & 1) ? Ai[PADIDX(pos)] : Ar[PADIDX(pos)];
        wrow[l] = v * scale;
    }
}

// Kernel 2a: in-place prefix sum along channels. Thread owns (b, lag); coalesced
// (adjacent threads = adjacent lags within a row).
__global__ __launch_bounds__(640) void k2a_prefix(float* __restrict__ ws) {
    const int b = blockIdx.x;
    const int l = threadIdx.x;
    if (l >= NXC) return;
    float* base = ws + (long)b * 128 * LST + l;
    float run = 0.0f;
#pragma unroll 4
    for (int c = 0; c < 128; ++c) {
        run += base[c * LST];
        base[c * LST] = run;
    }
}

// Kernel 2b: windowed value from prefix difference (2 rows instead of 20),
// then argmax/argmin reduce with first-index tie-break.
__global__ __launch_bounds__(128) void k2b_pick(const float* __restrict__ ws,
                                                const int* __restrict__ e1,
                                                const int* __restrict__ e2,
                                                float* __restrict__ out) {
    const int bc = blockIdx.x;
    const int b = bc >> 7, c = bc & 127;
    const int t = threadIdx.x;
    const float* Pb = ws + (long)(b * 128) * LST;
    const float* hi = Pb + (long)min(c + 9, 127) * LST;
    const bool has_lo = (c >= 11);
    const float* lo = Pb + (long)(has_lo ? (c - 11) : 0) * LST;

    float vmax = -3.0e38f; int imax = 0;
    float vmin = 3.0e38f;  int imin = 0;
    for (int l = t; l < NXC; l += 128) {
        float s = hi[l] - (has_lo ? lo[l] : 0.0f);
        s *= (1.0f / 20.0f);
        if (s > vmax) { vmax = s; imax = l; }
        if (s < vmin) { vmin = s; imin = l; }
    }

    __shared__ float smax[128], smin[128];
    __shared__ int   sxi[128], sni[128];
    smax[t] = vmax; sxi[t] = imax; smin[t] = vmin; sni[t] = imin;
    __syncthreads();
    for (int off = 64; off > 0; off >>= 1) {
        if (t < off) {
            float v2 = smax[t + off]; int i2 = sxi[t + off];
            if (v2 > smax[t] || (v2 == smax[t] && i2 < sxi[t])) { smax[t] = v2; sxi[t] = i2; }
            float u2 = smin[t + off]; int j2 = sni[t + off];
            if (u2 < smin[t] || (u2 == smin[t] && j2 < sni[t])) { smin[t] = u2; sni[t] = j2; }
        }
        __syncthreads();
    }
    if (t == 0) {
        float vx = smax[0], vn = smin[0];
        int ix = sxi[0], in_ = sni[0];
        bool ineg = fabsf(vn) > vx;
        float ccv = ineg ? vn : vx;
        int idx = ineg ? in_ : ix;
        out[bc] = ccv;
        out[4096 + bc] = (float)(idx - 299) * 0.01f;   // (idx - NLAG + 1) * DT
    }
    if (bc == 0 && t < 32) out[8192 + t] = (float)e1[t];
    if (bc == 1 && t < 32) out[8224 + t] = (float)e2[t];
}

extern "C" void kernel_launch(void* const* d_in, const int* in_sizes, int n_in,
                              void* d_out, int out_size, void* d_ws, size_t ws_size,
                              hipStream_t stream) {
    const float2* d1 = (const float2*)d_in[0];
    const float2* d2 = (const float2*)d_in[1];
    const int* e1 = (const int*)d_in[2];
    const int* e2 = (const int*)d_in[3];
    float* out = (float*)d_out;
    float* ws = (float*)d_ws;

    k1_fft<<<dim3(4096), dim3(256), 0, stream>>>(d1, d2, ws);
    k2a_prefix<<<dim3(32), dim3(640), 0, stream>>>(ws);
    k2b_pick<<<dim3(4096), dim3(128), 0, stream>>>(ws, e1, e2, out);
}